// Round 9
// baseline (170.939 us; speedup 1.0000x reference)
//
#include <hip/hip_runtime.h>
#include <math.h>

#define NN   1024
#define DD   32
#define EE   32768

// ---- workspace float offsets ----
#define O_EMB  0             // NN*32  in_emb (hyperboloid)  [dup path only]
#define O_LAMP 32768         // NN*32  lamp: lane0=lam-1, 1..31=lam*p
#define O_PARR 65536         // NN*32  parr: lane0=artanh(wn)/wn, 1..31=p_in
#define O_PN2  98304         // NN     |p_in|^2
#define O_PART 99328         // 1024*32 colsum partials [blk][col]
#define O_COLS 132096        // 64
#define O_NUMB 132160        // NN*32 (col0=den)      -- zero region start
#define O_ASUM 164928        // EE*32
#define O_CCNT 1213504       // NN*NN ints
#define O_NDUP 2262080       // 16 ints: [0]=ndup [1]=bdone [2]=ddone -- zero end
#define O_SLOT 2262096       // NN*NN ints (-1 fill)
#define O_DUPL 3310672       // EE ints (no init)
#define O_SBUF 3343440       // EE*32 es values
#define ZERO_I4 ((O_SLOT - O_NUMB)/4)   // 532484
#define SLOT_I4 (NN*NN/4)               // 262144

__device__ __forceinline__ float artanh_f(float x){
    x = fminf(fmaxf(x, -1.f + 1e-7f), 1.f - 1e-7f);
    return 0.5f * (log1pf(x) - log1pf(-x));
}
__device__ __forceinline__ float arcosh_f(float x){
    x = fmaxf(x, 1.f + 1e-7f);
    return logf(x + sqrtf(x*x - 1.f));
}
__device__ __forceinline__ float rsum(float v){
#pragma unroll
    for (int off=16; off>0; off>>=1) v += __shfl_xor(v, off, 32);
    return v;
}
__device__ __forceinline__ float logmap0_l(float xv, int lane){
    float ss = rsum(lane>=1 ? xv*xv : 0.f);
    float yn = sqrtf(fmaxf(ss, 1e-15f));
    float x0 = __shfl(xv, 0, 32);
    float s  = arcosh_f(x0) / yn;
    return lane>=1 ? s*xv : 0.f;
}
__device__ __forceinline__ float expmap0_proj_l(float uv, int lane){
    float ss = rsum(lane>=1 ? uv*uv : 0.f);
    float xn = sqrtf(fmaxf(ss, 1e-15f));
    float sh = sinhf(xn)/xn;
    float o  = sh*uv;
    float ys = rsum(lane>=1 ? o*o : 0.f);
    float o0 = sqrtf(fmaxf(1.f+ys, 1e-7f));
    return lane==0 ? o0 : o;
}
// h_proj(h_mobius_add) with tangent u given directly (logmap0(expmap0(b)) == b)
__device__ __forceinline__ float mobius_add_u_l(float xv, float uv, int lane){
    float u  = lane>=1 ? uv : 0.f;
    float x1 = lane>=1 ? xv : 0.f;
    float ss = rsum(x1*x1);
    float xn = sqrtf(fmaxf(ss, 1e-15f));
    float alpha = rsum(x1*u) / xn;
    float x0 = __shfl(xv, 0, 32);
    float coef = alpha * (1.f - x0) / xn;
    float w  = lane>=1 ? u - coef*xv : 0.f;
    float ux = rsum(x1*w);
    float w0 = ux / fmaxf(x0, 1e-7f);
    float wsq = rsum(w*w);
    float nu = sqrtf(fmaxf(wsq - w0*w0, 1e-15f));
    float th = fmaxf(nu, 1e-15f);
    float ch = coshf(th), shq = sinhf(th)/th;
    float o  = ch*xv + shq*w;
    float ys = rsum(lane>=1 ? o*o : 0.f);
    float o0 = sqrtf(fmaxf(1.f+ys, 1e-7f));
    return lane==0 ? o0 : o;
}
__device__ __forceinline__ float att_of(float ac, float w, float m, int lane){
    float ad = __shfl(ac,0,32)+1.f;
    float wd = m*__shfl(w,0,32)+1.f;
    float pa_ = lane>=1 ? ac/ad : 0.f;
    float pw  = lane>=1 ? m*w/wd : 0.f;
    float dot = rsum(pa_*pw);
    float wns = rsum(pw*pw);
    float wn  = sqrtf(fmaxf(wns, 1e-15f));
    return tanhf(dot/wn * artanh_f(wn));
}

// ---- A: fill (blocks 128..1023) + per-node precompute (blocks 0..127) ----
__global__ __launch_bounds__(256) void k_a(const float* __restrict__ x,
        const float* __restrict__ Wd, const float* __restrict__ bd,
        float* __restrict__ ws){
    __shared__ float smem[5152];
    int tid = threadIdx.x, lane = tid&31, grp = tid>>5, bid = blockIdx.x;
    if (bid >= 128){
        int4* zb = (int4*)(ws + O_NUMB);
        int4* sb = (int4*)(ws + O_SLOT);
        int t0 = (bid-128)*256 + tid, nthr = 896*256;
        int4 zz; zz.x=0; zz.y=0; zz.z=0; zz.w=0;
        int4 mm; mm.x=-1; mm.y=-1; mm.z=-1; mm.w=-1;
        for (int k=t0; k<ZERO_I4; k+=nthr) zb[k]=zz;
        for (int k=t0; k<SLOT_I4; k+=nthr) sb[k]=mm;
        return;
    }
    float* xs  = smem;           // [8][128]
    float* Wds = smem + 1024;    // [32][129]
    float* in_emb = ws + O_EMB;
    float* lamp   = ws + O_LAMP;
    float* parr   = ws + O_PARR;
    float* pn2    = ws + O_PN2;
    for (int idx=tid; idx<32*128; idx+=256) Wds[(idx>>7)*129+(idx&127)] = Wd[idx];
    int node = bid*8 + grp;
#pragma unroll
    for (int r=0;r<4;++r) xs[grp*128+lane+32*r] = x[node*128+lane+32*r];
    __syncthreads();
    float ssp = 0.f;
#pragma unroll
    for (int r=0;r<4;++r){ int d=lane+32*r; float t=xs[grp*128+d]; if (d>=1) ssp += t*t; }
    float ss = rsum(ssp);
    float yn = sqrtf(fmaxf(ss, 1e-15f));
    float x0 = xs[grp*128];
    float scale = arcosh_f(x0)/yn;
    float acc = 0.f;
    for (int d=1; d<128; ++d) acc += Wds[lane*129+d]*xs[grp*128+d];
    float v = lane>=1 ? acc*scale : 0.f;
    float res = expmap0_proj_l(v, lane);
    float o   = mobius_add_u_l(res, bd[lane], lane);
    in_emb[node*32+lane] = o;
    float o0 = __shfl(o, 0, 32);
    float p  = lane>=1 ? o/(o0+1.f) : 0.f;     // p_in
    float sq = rsum(p*p);
    float lam = 2.f/fmaxf(1.f-sq, 1e-15f);
    lamp[node*32+lane] = lane>=1 ? lam*p : lam-1.f;
    float wn = sqrtf(fmaxf(sq, 1e-15f));
    float attw = artanh_f(wn)/wn;
    parr[node*32+lane] = lane>=1 ? p : attw;
    if (lane==0) pn2[node] = sq;
}

// ---- B: per-edge logits es; slot claim+count; partials; tail block -> colsum ----
__global__ __launch_bounds__(256) void k_b(const int* __restrict__ edges,
        const float* __restrict__ Wa, float* __restrict__ ws){
    __shared__ float Was[32*65];
    __shared__ float cats[8*64];
    __shared__ float parts[8*32];
    __shared__ float red[256];
    __shared__ int last_s;
    const float* parr = ws + O_PARR;
    const float* pn2  = ws + O_PN2;
    float* sbuf    = ws + O_SBUF;
    float* partial = ws + O_PART;
    float* colsum  = ws + O_COLS;
    int* slotmap = (int*)(ws + O_SLOT);
    int* cellcnt = (int*)(ws + O_CCNT);
    int* bdone   = (int*)(ws + O_NDUP) + 1;
    int tid = threadIdx.x, lane = tid&31, grp = tid>>5, bid = blockIdx.x;
    for (int idx=tid; idx<32*63; idx+=256){ int k=idx/63, c=idx-63*k; Was[k*65+c]=Wa[idx]; }
    __syncthreads();
    float colp = 0.f;
#pragma unroll
    for (int k=0;k<4;++k){
        int e = bid*32 + k*8 + grp;
        int i = edges[e], j = edges[EE+e];
        float pi = lane>=1 ? parr[i*32+lane] : 0.f;
        float pj = lane>=1 ? parr[j*32+lane] : 0.f;
        float sq = pn2[i] + pn2[j];
        float dnm = fmaxf(1.f-sq, 1e-15f);
        float c0  = (1.f+sq)/dnm;
        float ssy = 4.f*sq/(dnm*dnm);
        float ynn = sqrtf(fmaxf(ssy, 1e-15f));
        float sc2 = arcosh_f(c0)/ynn;
        float t2 = 2.f/dnm;
        // cats[grp] is group-private; groups 2g/2g+1 share one wave64 -> no barrier
        if (lane>=1){ cats[grp*64+lane-1]=t2*pi; cats[grp*64+30+lane]=t2*pj; }
        float acc = 0.f;
        for (int t=0;t<62;++t) acc += Was[lane*65+1+t]*cats[grp*64+t];
        float v = acc*sc2;
        v = v>=0.f ? v : 0.2f*v;                 // leaky (logmap/expmap cancel)
        float es = lane>=1 ? expf(v) : 0.f;      // bounded logits: no max pass
        sbuf[e*32+lane] = es;
        colp += es;
        if (lane==0){
            atomicMax(&slotmap[i*NN+j], e);
            atomicAdd(&cellcnt[i*NN+j], 1);
        }
    }
    parts[grp*32+lane] = colp;
    __syncthreads();
    if (grp==0){
        float s8 = 0.f;
#pragma unroll
        for (int g=0; g<8; ++g) s8 += parts[g*32+lane];
        partial[bid*32+lane] = s8;
        __threadfence();                         // writer-side release
    }
    __syncthreads();
    if (tid==0) last_s = atomicAdd(bdone, 1);
    __syncthreads();
    if (last_s != 1023) return;
    // tail block: reduce 1024x32 partials -> colsum
    __threadfence();                             // acquire
    int col = tid & 31, rb = tid >> 5;
    float s = 0.f;
    for (int k=rb; k<1024; k+=8) s += partial[k*32+col];
    red[tid]=s; __syncthreads();
#pragma unroll
    for (int off=128; off>=32; off>>=1){
        if (tid<off) red[tid]+=red[tid+off];
        __syncthreads();
    }
    if (tid<32) colsum[tid]=red[tid];
}

// ---- D: softmax+att; unique cells closed-form; dup deposit; last-8 tail -> dups ----
__global__ __launch_bounds__(256) void k_d(const int* __restrict__ edges,
        float* __restrict__ ws){
    __shared__ int last_s;
    const float* sbuf   = ws + O_SBUF;
    const float* colsum = ws + O_COLS;
    const float* parr   = ws + O_PARR;
    const float* lamp   = ws + O_LAMP;
    const float* in_emb = ws + O_EMB;
    float* numb   = ws + O_NUMB;
    float* asum   = ws + O_ASUM;
    int* slotmap  = (int*)(ws + O_SLOT);
    int* cellcnt  = (int*)(ws + O_CCNT);
    int* ndup     = (int*)(ws + O_NDUP);
    int* ddone    = (int*)(ws + O_NDUP) + 2;
    int* duplist  = (int*)(ws + O_DUPL);
    int tid = threadIdx.x, lane = tid&31, grp = tid>>5, bid = blockIdx.x;
    float csum = lane>=1 ? colsum[lane] : 1.f;
#pragma unroll
    for (int k=0;k<4;++k){
        int e = bid*32 + k*8 + grp;
        int i = edges[e], j = edges[EE+e];
        float es = sbuf[e*32+lane];
        float u = lane>=1 ? es/csum : 0.f;
        int cnt = cellcnt[i*NN+j];
        if (cnt == 1){
            float th2 = rsum(u*u);
            float th = sqrtf(fmaxf(th2, 1e-15f));
            float f = tanhf(0.5f*th)/th;
            float pj = parr[j*32+lane];
            float attw = __shfl(pj, 0, 32);
            float dotu = rsum(lane>=1 ? u*pj : 0.f);
            float att = tanhf(f*dotu*attw);
            atomicAdd(&numb[i*32+lane], att*lamp[j*32+lane]);
        } else {
            float a = expmap0_proj_l(u, lane);
            int slot = slotmap[i*NN+j];
            atomicAdd(&asum[slot*32+lane], a);
            if (lane==0 && slot==e){
                int t = atomicAdd(ndup, 1);
                duplist[t] = e;
            }
        }
    }
    __threadfence();                             // release deposits/duplist
    __syncthreads();
    if (tid==0) last_s = atomicAdd(ddone, 1);
    __syncthreads();
    int rank = last_s - (1024-8);
    if (rank < 0) return;
    // among last 8 blocks: wait for all 1024, then process dup cells
    if (tid==0){ while (atomicAdd(ddone, 0) < 1024) {} }
    __syncthreads();
    __threadfence();                             // acquire
    int n = *ndup;
    int gid = rank*8 + grp;                      // 64 groups over last 8 blocks
    for (int idx=gid; idx<n; idx+=64){
        int e = duplist[idx];
        int i = edges[e], j = edges[EE+e];
        float m  = (float)cellcnt[i*NN+j];
        float ac = asum[e*32+lane];
        float w  = in_emb[j*32+lane];
        float att = att_of(ac, w, m, lane);
        atomicAdd(&numb[i*32+lane], att*lamp[j*32+lane]);
    }
}

// ---- F: per-node epilogue ----
__global__ __launch_bounds__(256) void k_f(const float* __restrict__ Wo,
        const float* __restrict__ bo, float* __restrict__ out,
        float* __restrict__ ws){
    __shared__ float Wos[32*33];
    const float* numb = ws + O_NUMB;
    int tid = threadIdx.x, lane = tid&31, grp = tid>>5;
    int i = blockIdx.x*8 + grp;
    for (int idx=tid; idx<1024; idx+=256) Wos[(idx>>5)*33+(idx&31)] = Wo[idx];
    __syncthreads();
    float nb = numb[i*32+lane];
    float dn = __shfl(nb, 0, 32);
    if (fabsf(dn) < 1e-10f) dn = 1e-10f;
    float g = lane>=1 ? nb/dn : 0.f;
    float gss = rsum(g*g);
    float gn = sqrtf(fmaxf(gss, 1e-15f));
    float scl = tanhf(0.5f*artanh_f(gn))/gn;
    g *= scl;                                   // p_out
    float sq = rsum(g*g);
    float dnm = fmaxf(1.f-sq, 1e-15f);
    float h = lane==0 ? (1.f+sq)/dnm : 2.f*g/dnm;
    float r = logmap0_l(h, lane);
    float acc = 0.f;
#pragma unroll
    for (int d=1; d<32; ++d){ float rb = __shfl(r, d, 32); acc += Wos[lane*33+d]*rb; }
    float v = lane>=1 ? acc : 0.f;
    float res = expmap0_proj_l(v, lane);
    float o   = mobius_add_u_l(res, bo[lane], lane);
    out[i*32+lane] = o;
}

extern "C" void kernel_launch(void* const* d_in, const int* in_sizes, int n_in,
                              void* d_out, int out_size, void* d_ws, size_t ws_size,
                              hipStream_t stream) {
    const float* x  = (const float*)d_in[0];
    const int* edges = (const int*)d_in[1];
    const float* Wd = (const float*)d_in[2];
    const float* bd = (const float*)d_in[3];
    const float* Wa = (const float*)d_in[4];
    const float* Wo = (const float*)d_in[5];
    const float* bo = (const float*)d_in[6];
    float* out = (float*)d_out;
    float* ws  = (float*)d_ws;

    k_a<<<1024, 256, 0, stream>>>(x, Wd, bd, ws);
    k_b<<<1024, 256, 0, stream>>>(edges, Wa, ws);
    k_d<<<1024, 256, 0, stream>>>(edges, ws);
    k_f<<<NN/8, 256, 0, stream>>>(Wo, bo, out, ws);
}

// Round 10
// 57.571 us; speedup vs baseline: 2.9692x; 2.9692x over previous
//
#include <hip/hip_runtime.h>
#include <math.h>

#define NN   1024
#define DD   32
#define EE   32768

// ---- workspace float offsets ----
#define O_EMB  0             // NN*32  in_emb (hyperboloid)  [dup path only]
#define O_LAMP 32768         // NN*32  lamp: lane0=lam-1, 1..31=lam*p
#define O_PARR 65536         // NN*32  parr: lane0=artanh(wn)/wn, 1..31=p_in
#define O_PN2  98304         // NN     |p_in|^2
#define O_AB   99328         // NN*64  per-node Wa half-dots [A(32) | B(32)]
#define O_PART 164864        // 1024*32 colsum partials [blk][col]
#define O_COLS 197632        // 64
#define O_NUMB 197696        // NN*32 (col0=den)      -- zero region start
#define O_ASUM 230464        // EE*32
#define O_CCNT 1279040       // NN*NN ints
#define O_NDUP 2327616       // 16 ints: [0]=ndup     -- zero region end
#define O_SLOT 2327632       // NN*NN ints (-1 fill)
#define O_DUPL 3376208       // EE ints (no init)
#define O_SBUF 3408976       // EE*32 es values
#define ZERO_I4 ((O_SLOT - O_NUMB)/4)   // 532484
#define SLOT_I4 (NN*NN/4)               // 262144

__device__ __forceinline__ float artanh_f(float x){
    x = fminf(fmaxf(x, -1.f + 1e-7f), 1.f - 1e-7f);
    return 0.5f * (log1pf(x) - log1pf(-x));
}
__device__ __forceinline__ float arcosh_f(float x){
    x = fmaxf(x, 1.f + 1e-7f);
    return logf(x + sqrtf(x*x - 1.f));
}
__device__ __forceinline__ float rsum(float v){
#pragma unroll
    for (int off=16; off>0; off>>=1) v += __shfl_xor(v, off, 32);
    return v;
}
__device__ __forceinline__ float logmap0_l(float xv, int lane){
    float ss = rsum(lane>=1 ? xv*xv : 0.f);
    float yn = sqrtf(fmaxf(ss, 1e-15f));
    float x0 = __shfl(xv, 0, 32);
    float s  = arcosh_f(x0) / yn;
    return lane>=1 ? s*xv : 0.f;
}
__device__ __forceinline__ float expmap0_proj_l(float uv, int lane){
    float ss = rsum(lane>=1 ? uv*uv : 0.f);
    float xn = sqrtf(fmaxf(ss, 1e-15f));
    float sh = sinhf(xn)/xn;
    float o  = sh*uv;
    float ys = rsum(lane>=1 ? o*o : 0.f);
    float o0 = sqrtf(fmaxf(1.f+ys, 1e-7f));
    return lane==0 ? o0 : o;
}
// h_proj(h_mobius_add) with tangent u given directly (logmap0(expmap0(b)) == b)
__device__ __forceinline__ float mobius_add_u_l(float xv, float uv, int lane){
    float u  = lane>=1 ? uv : 0.f;
    float x1 = lane>=1 ? xv : 0.f;
    float ss = rsum(x1*x1);
    float xn = sqrtf(fmaxf(ss, 1e-15f));
    float alpha = rsum(x1*u) / xn;
    float x0 = __shfl(xv, 0, 32);
    float coef = alpha * (1.f - x0) / xn;
    float w  = lane>=1 ? u - coef*xv : 0.f;
    float ux = rsum(x1*w);
    float w0 = ux / fmaxf(x0, 1e-7f);
    float wsq = rsum(w*w);
    float nu = sqrtf(fmaxf(wsq - w0*w0, 1e-15f));
    float th = fmaxf(nu, 1e-15f);
    float ch = coshf(th), shq = sinhf(th)/th;
    float o  = ch*xv + shq*w;
    float ys = rsum(lane>=1 ? o*o : 0.f);
    float o0 = sqrtf(fmaxf(1.f+ys, 1e-7f));
    return lane==0 ? o0 : o;
}
__device__ __forceinline__ float att_of(float ac, float w, float m, int lane){
    float ad = __shfl(ac,0,32)+1.f;
    float wd = m*__shfl(w,0,32)+1.f;
    float pa_ = lane>=1 ? ac/ad : 0.f;
    float pw  = lane>=1 ? m*w/wd : 0.f;
    float dot = rsum(pa_*pw);
    float wns = rsum(pw*pw);
    float wn  = sqrtf(fmaxf(wns, 1e-15f));
    return tanhf(dot/wn * artanh_f(wn));
}

// ---- A: fill (blocks 128..1023) + per-node precompute (blocks 0..127) ----
__global__ __launch_bounds__(256) void k_a(const float* __restrict__ x,
        const float* __restrict__ Wd, const float* __restrict__ bd,
        const float* __restrict__ Wa, float* __restrict__ ws){
    __shared__ float smem[7488];   // xs[1024] Wds[4128] Was[2080] pbuf[256]
    int tid = threadIdx.x, lane = tid&31, grp = tid>>5, bid = blockIdx.x;
    if (bid >= 128){
        int4* zb = (int4*)(ws + O_NUMB);
        int4* sb = (int4*)(ws + O_SLOT);
        int t0 = (bid-128)*256 + tid, nthr = 896*256;
        int4 zz; zz.x=0; zz.y=0; zz.z=0; zz.w=0;
        int4 mm; mm.x=-1; mm.y=-1; mm.z=-1; mm.w=-1;
        for (int k=t0; k<ZERO_I4; k+=nthr) zb[k]=zz;
        for (int k=t0; k<SLOT_I4; k+=nthr) sb[k]=mm;
        return;
    }
    float* xs   = smem;            // [8][128]
    float* Wds  = smem + 1024;     // [32][129]
    float* Was  = smem + 5152;     // [32][65]
    float* pbuf = smem + 7232;     // [8][32]
    float* in_emb = ws + O_EMB;
    float* lamp   = ws + O_LAMP;
    float* parr   = ws + O_PARR;
    float* pn2    = ws + O_PN2;
    float* AB     = ws + O_AB;
    for (int idx=tid; idx<32*128; idx+=256) Wds[(idx>>7)*129+(idx&127)] = Wd[idx];
    for (int idx=tid; idx<32*63; idx+=256){ int k=idx/63, c=idx-63*k; Was[k*65+c]=Wa[idx]; }
    int node = bid*8 + grp;
#pragma unroll
    for (int r=0;r<4;++r) xs[grp*128+lane+32*r] = x[node*128+lane+32*r];
    __syncthreads();
    float ssp = 0.f;
#pragma unroll
    for (int r=0;r<4;++r){ int d=lane+32*r; float t=xs[grp*128+d]; if (d>=1) ssp += t*t; }
    float ss = rsum(ssp);
    float yn = sqrtf(fmaxf(ss, 1e-15f));
    float x0 = xs[grp*128];
    float scale = arcosh_f(x0)/yn;
    float acc = 0.f;
    for (int d=1; d<128; ++d) acc += Wds[lane*129+d]*xs[grp*128+d];
    float v = lane>=1 ? acc*scale : 0.f;
    float res = expmap0_proj_l(v, lane);
    float o   = mobius_add_u_l(res, bd[lane], lane);
    in_emb[node*32+lane] = o;
    float o0 = __shfl(o, 0, 32);
    float p  = lane>=1 ? o/(o0+1.f) : 0.f;     // p_in
    float sq = rsum(p*p);
    float lam = 2.f/fmaxf(1.f-sq, 1e-15f);
    lamp[node*32+lane] = lane>=1 ? lam*p : lam-1.f;
    float wn = sqrtf(fmaxf(sq, 1e-15f));
    float attw = artanh_f(wn)/wn;
    parr[node*32+lane] = lane>=1 ? p : attw;
    if (lane==0) pn2[node] = sq;
    // per-node Wa half-dots: A[k]=sum_d Wa[k][d]*p[d], B[k]=sum_d Wa[k][31+d]*p[d]
    pbuf[grp*32+lane] = p;                     // group-private, intra-wave RAW
    float Ak = 0.f, Bk = 0.f;
    for (int d=1; d<32; ++d){
        float pd = pbuf[grp*32+d];
        Ak += Was[lane*65+d]*pd;
        Bk += Was[lane*65+31+d]*pd;
    }
    AB[node*64+lane]    = Ak;
    AB[node*64+32+lane] = Bk;
}

// ---- B: per-edge logits es = exp(leaky(sc2*t2*(A_i+B_j))); slot claim; partials ----
__global__ __launch_bounds__(256) void k_b(const int* __restrict__ edges,
        float* __restrict__ ws){
    __shared__ float parts[8*32];
    const float* pn2 = ws + O_PN2;
    const float* AB  = ws + O_AB;
    float* sbuf    = ws + O_SBUF;
    float* partial = ws + O_PART;
    int* slotmap = (int*)(ws + O_SLOT);
    int* cellcnt = (int*)(ws + O_CCNT);
    int tid = threadIdx.x, lane = tid&31, grp = tid>>5, bid = blockIdx.x;
    float colp = 0.f;
#pragma unroll
    for (int k=0;k<4;++k){
        int e = bid*32 + k*8 + grp;
        int i = edges[e], j = edges[EE+e];
        float sq = pn2[i] + pn2[j];
        float dnm = fmaxf(1.f-sq, 1e-15f);
        float c0  = (1.f+sq)/dnm;
        float ssy = 4.f*sq/(dnm*dnm);
        float ynn = sqrtf(fmaxf(ssy, 1e-15f));
        float scl = arcosh_f(c0)/ynn * 2.f/dnm;     // sc2 * t2
        float Ai = AB[i*64+lane];
        float Bj = AB[j*64+32+lane];
        float v = scl*(Ai+Bj);
        v = v>=0.f ? v : 0.2f*v;                    // leaky (logmap/expmap cancel)
        float es = lane>=1 ? expf(v) : 0.f;         // bounded logits: no max pass
        sbuf[e*32+lane] = es;
        colp += es;
        if (lane==0){
            atomicMax(&slotmap[i*NN+j], e);
            atomicAdd(&cellcnt[i*NN+j], 1);
        }
    }
    parts[grp*32+lane] = colp;
    __syncthreads();
    if (grp==0){
        float s8 = 0.f;
#pragma unroll
        for (int g=0; g<8; ++g) s8 += parts[g*32+lane];
        partial[bid*32+lane] = s8;                  // coalesced, racefree
    }
}

// ---- C: reduce 1024 partials/column -> colsum ----
__global__ __launch_bounds__(256) void k_c(float* __restrict__ ws){
    __shared__ float red[256];
    const float* partial = ws + O_PART;
    float* colsum = ws + O_COLS;
    int tid = threadIdx.x, col = blockIdx.x;
    float s = 0.f;
#pragma unroll
    for (int r=0;r<4;++r) s += partial[(tid + r*256)*32 + col];
    red[tid]=s; __syncthreads();
    for (int off=128; off>0; off>>=1){
        if (tid<off) red[tid]+=red[tid+off];
        __syncthreads();
    }
    if (tid==0) colsum[col]=red[0];
}

// ---- D: softmax; unique cells closed-form att; dup deposits + duplist ----
__global__ __launch_bounds__(256) void k_d(const int* __restrict__ edges,
        float* __restrict__ ws){
    const float* sbuf   = ws + O_SBUF;
    const float* colsum = ws + O_COLS;
    const float* parr   = ws + O_PARR;
    const float* lamp   = ws + O_LAMP;
    float* numb   = ws + O_NUMB;
    float* asum   = ws + O_ASUM;
    int* slotmap  = (int*)(ws + O_SLOT);
    int* cellcnt  = (int*)(ws + O_CCNT);
    int* ndup     = (int*)(ws + O_NDUP);
    int* duplist  = (int*)(ws + O_DUPL);
    int tid = threadIdx.x, lane = tid&31, grp = tid>>5, bid = blockIdx.x;
    float csum = lane>=1 ? colsum[lane] : 1.f;
#pragma unroll
    for (int k=0;k<4;++k){
        int e = bid*32 + k*8 + grp;
        int i = edges[e], j = edges[EE+e];
        float es = sbuf[e*32+lane];
        float u = lane>=1 ? es/csum : 0.f;
        int cnt = cellcnt[i*NN+j];
        if (cnt == 1){
            float th2 = rsum(u*u);
            float th = sqrtf(fmaxf(th2, 1e-15f));
            float f = tanhf(0.5f*th)/th;
            float pj = parr[j*32+lane];
            float attw = __shfl(pj, 0, 32);
            float dotu = rsum(lane>=1 ? u*pj : 0.f);
            float att = tanhf(f*dotu*attw);
            atomicAdd(&numb[i*32+lane], att*lamp[j*32+lane]);
        } else {
            float a = expmap0_proj_l(u, lane);
            int slot = slotmap[i*NN+j];
            atomicAdd(&asum[slot*32+lane], a);
            if (lane==0 && slot==e){
                int t = atomicAdd(ndup, 1);
                duplist[t] = e;
            }
        }
    }
}

// ---- E: duplicate-cell winners ----
__global__ __launch_bounds__(256) void k_e(const int* __restrict__ edges,
        float* __restrict__ ws){
    const float* asum   = ws + O_ASUM;
    const float* in_emb = ws + O_EMB;
    const float* lamp   = ws + O_LAMP;
    float* numb  = ws + O_NUMB;
    int* cellcnt = (int*)(ws + O_CCNT);
    int* ndup    = (int*)(ws + O_NDUP);
    int* duplist = (int*)(ws + O_DUPL);
    int tid = threadIdx.x, lane = tid&31;
    int gid = (blockIdx.x*256 + tid) >> 5;   // 64 groups
    int n = *ndup;
    for (int idx=gid; idx<n; idx+=64){
        int e = duplist[idx];
        int i = edges[e], j = edges[EE+e];
        float m  = (float)cellcnt[i*NN+j];
        float ac = asum[e*32+lane];
        float w  = in_emb[j*32+lane];
        float att = att_of(ac, w, m, lane);
        atomicAdd(&numb[i*32+lane], att*lamp[j*32+lane]);
    }
}

// ---- F: per-node epilogue ----
__global__ __launch_bounds__(256) void k_f(const float* __restrict__ Wo,
        const float* __restrict__ bo, float* __restrict__ out,
        float* __restrict__ ws){
    __shared__ float Wos[32*33];
    const float* numb = ws + O_NUMB;
    int tid = threadIdx.x, lane = tid&31, grp = tid>>5;
    int i = blockIdx.x*8 + grp;
    for (int idx=tid; idx<1024; idx+=256) Wos[(idx>>5)*33+(idx&31)] = Wo[idx];
    __syncthreads();
    float nb = numb[i*32+lane];
    float dn = __shfl(nb, 0, 32);
    if (fabsf(dn) < 1e-10f) dn = 1e-10f;
    float g = lane>=1 ? nb/dn : 0.f;
    float gss = rsum(g*g);
    float gn = sqrtf(fmaxf(gss, 1e-15f));
    float scl = tanhf(0.5f*artanh_f(gn))/gn;
    g *= scl;                                   // p_out
    float sq = rsum(g*g);
    float dnm = fmaxf(1.f-sq, 1e-15f);
    float h = lane==0 ? (1.f+sq)/dnm : 2.f*g/dnm;
    float r = logmap0_l(h, lane);
    float acc = 0.f;
#pragma unroll
    for (int d=1; d<32; ++d){ float rb = __shfl(r, d, 32); acc += Wos[lane*33+d]*rb; }
    float v = lane>=1 ? acc : 0.f;
    float res = expmap0_proj_l(v, lane);
    float o   = mobius_add_u_l(res, bo[lane], lane);
    out[i*32+lane] = o;
}

extern "C" void kernel_launch(void* const* d_in, const int* in_sizes, int n_in,
                              void* d_out, int out_size, void* d_ws, size_t ws_size,
                              hipStream_t stream) {
    const float* x  = (const float*)d_in[0];
    const int* edges = (const int*)d_in[1];
    const float* Wd = (const float*)d_in[2];
    const float* bd = (const float*)d_in[3];
    const float* Wa = (const float*)d_in[4];
    const float* Wo = (const float*)d_in[5];
    const float* bo = (const float*)d_in[6];
    float* out = (float*)d_out;
    float* ws  = (float*)d_ws;

    k_a<<<1024, 256, 0, stream>>>(x, Wd, bd, Wa, ws);
    k_b<<<1024, 256, 0, stream>>>(edges, ws);
    k_c<<<32,   256, 0, stream>>>(ws);
    k_d<<<1024, 256, 0, stream>>>(edges, ws);
    k_e<<<8,    256, 0, stream>>>(edges, ws);
    k_f<<<NN/8, 256, 0, stream>>>(Wo, bo, out, ws);
}